// Round 9
// baseline (346.261 us; speedup 1.0000x reference)
//
#include <hip/hip_runtime.h>
#include <hip/hip_bf16.h>
#include <stdint.h>

typedef __bf16 bf16x8 __attribute__((ext_vector_type(8)));
typedef float f32x4 __attribute__((ext_vector_type(4)));
typedef float f32x4v __attribute__((ext_vector_type(4)));       // for nontemporal builtins
typedef unsigned short u16x4 __attribute__((ext_vector_type(4)));

// native RNE f32->bf16 (gfx950: v_cvt_pk_bf16_f32)
__device__ __forceinline__ uint16_t f2bf(float f){
  __bf16 h = (__bf16)f;
  return __builtin_bit_cast(uint16_t, h);
}

__device__ __forceinline__ void gld_lds16(const void* g, void* l){
  __builtin_amdgcn_global_load_lds((const __attribute__((address_space(1))) void*)g,
                                   (__attribute__((address_space(3))) void*)l, 16, 0, 0);
}

// ------------- f32 -> bf16 conversion, two tensors per launch -------------
// nt loads (read-once) + nt stores (consumed by a later kernel; don't pollute L2).
__global__ void convert2(const float* __restrict__ s1, uint16_t* __restrict__ d1, int n4_1,
                         const float* __restrict__ s2, uint16_t* __restrict__ d2, int n4_2){
  int i = blockIdx.x * blockDim.x + threadIdx.x;
  const float* s; uint16_t* d;
  if (i < n4_1) { s = s1; d = d1; }
  else { i -= n4_1; if (i >= n4_2) return; s = s2; d = d2; }
  f32x4v v = __builtin_nontemporal_load(((const f32x4v*)s) + i);
  u16x4 o;
  o.x = f2bf(v.x); o.y = f2bf(v.y); o.z = f2bf(v.z); o.w = f2bf(v.w);
  __builtin_nontemporal_store(o, ((u16x4*)d) + i);
}

// ---------------- bf16 bt-GEMM, 2-phase double-buffered (BK=64) ----------
// C[m][n] = sum_k A[m][k]*W[n][k] + bias[n]
// A: [8192][1024] bf16 row-major. W: [1024][1024] bf16 row-major (rows are n).
// mode 0: out bf16 row-major [8192][1024], value (acc+bias)*oscale
// mode 2: out = Vt layout [4096][2048] bf16: row = b*1024 + n, col = l
// mode 3: out f32 row-major [8192][1024]
// C stores are NONTEMPORAL: streaming writes must not evict the A/W panels
// from the 4MB per-XCD L2 (A-panel reuse across the 8 n-blocks sharing m0 is
// the difference between 36MB and 268MB of HBM per GEMM).
__launch_bounds__(256, 2)
__global__ void gemm_bt(const uint16_t* __restrict__ A, const uint16_t* __restrict__ W,
                        const float* __restrict__ bias, void* __restrict__ out, int mode,
                        float oscale)
{
  __shared__ uint16_t As[2][128 * 64];   // 2 x 16 KB
  __shared__ uint16_t Ws[2][128 * 64];   // 2 x 16 KB
  const int tid = threadIdx.x;
  const int wave = tid >> 6, lane = tid & 63;
  const int g = lane >> 4, li = lane & 15;
  const int m0 = blockIdx.x * 128, n0 = blockIdx.y * 128;
  const int wr = (wave >> 1) * 64, wc = (wave & 1) * 64;

  f32x4 acc[4][4];
#pragma unroll
  for (int m = 0; m < 4; m++)
#pragma unroll
    for (int n = 0; n < 4; n++) acc[m][n] = f32x4{0.f, 0.f, 0.f, 0.f};

  // staging: chunk j*256+tid; row = chunk>>3, c = chunk&7, src chunk = c^(row&7)
  const uint16_t* Asrc[4];
  const uint16_t* Wsrc[4];
  int cid[4];
#pragma unroll
  for (int j = 0; j < 4; j++) {
    cid[j] = j * 256 + tid;
    int row = cid[j] >> 3, c = cid[j] & 7;
    int sc = c ^ (row & 7);
    Asrc[j] = A + (size_t)(m0 + row) * 1024 + sc * 8;
    Wsrc[j] = W + (size_t)(n0 + row) * 1024 + sc * 8;
  }

  // prologue: stage tile 0 into buffer 0
#pragma unroll
  for (int j = 0; j < 4; j++) {
    gld_lds16(Asrc[j], (char*)As[0] + cid[j] * 16);
    gld_lds16(Wsrc[j], (char*)Ws[0] + cid[j] * 16);
  }
  __syncthreads();

  for (int t = 0; t < 16; t++) {
    const int cur = t & 1;
    if (t < 15) {
      const int k1 = (t + 1) * 64;
      const int nxt = cur ^ 1;
#pragma unroll
      for (int j = 0; j < 4; j++) {
        gld_lds16(Asrc[j] + k1, (char*)As[nxt] + cid[j] * 16);
        gld_lds16(Wsrc[j] + k1, (char*)Ws[nxt] + cid[j] * 16);
      }
    }

    const char* Ab = (const char*)As[cur];
    const char* Wb = (const char*)Ws[cur];
#pragma unroll
    for (int kh = 0; kh < 2; kh++) {
      bf16x8 a[4], bfr[4];
#pragma unroll
      for (int m = 0; m < 4; m++) {
        int row = wr + m * 16 + li;
        int ch = (kh * 4 + g) ^ (row & 7);
        a[m] = *(const bf16x8*)(Ab + row * 128 + ch * 16);
      }
#pragma unroll
      for (int n = 0; n < 4; n++) {
        int row = wc + n * 16 + li;
        int ch = (kh * 4 + g) ^ (row & 7);
        bfr[n] = *(const bf16x8*)(Wb + row * 128 + ch * 16);
      }
#pragma unroll
      for (int m = 0; m < 4; m++)
#pragma unroll
        for (int n = 0; n < 4; n++)
          acc[m][n] = __builtin_amdgcn_mfma_f32_16x16x32_bf16(a[m], bfr[n], acc[m][n], 0, 0, 0);
    }
    __syncthreads();
  }

  // epilogue; C element (row = m0+wr+m*16+g*4+r, col = n0+wc+n*16+li)
  if (mode == 0) {
    uint16_t* O = (uint16_t*)out;
#pragma unroll
    for (int n = 0; n < 4; n++) {
      int col = n0 + wc + n * 16 + li;
      float bv = bias[col];
#pragma unroll
      for (int m = 0; m < 4; m++) {
        int row = m0 + wr + m * 16 + g * 4;
#pragma unroll
        for (int r = 0; r < 4; r++)
          __builtin_nontemporal_store(f2bf((acc[m][n][r] + bv) * oscale),
                                      &O[(size_t)(row + r) * 1024 + col]);
      }
    }
  } else if (mode == 2) {
    uint16_t* O = (uint16_t*)out;
#pragma unroll
    for (int n = 0; n < 4; n++) {
      int col = n0 + wc + n * 16 + li;
      float bv = bias[col];
#pragma unroll
      for (int m = 0; m < 4; m++) {
        int mg = m0 + wr + m * 16 + g * 4;
        int bidx = mg >> 11;          // batch
        int l = mg & 2047;            // position (4 consecutive r's)
        u16x4 pk;
        pk.x = f2bf(acc[m][n][0] + bv);
        pk.y = f2bf(acc[m][n][1] + bv);
        pk.z = f2bf(acc[m][n][2] + bv);
        pk.w = f2bf(acc[m][n][3] + bv);
        __builtin_nontemporal_store(pk,
            (u16x4*)(O + ((size_t)bidx * 1024 + col) * 2048 + l));
      }
    }
  } else {
    float* O = (float*)out;
#pragma unroll
    for (int n = 0; n < 4; n++) {
      int col = n0 + wc + n * 16 + li;
      float bv = bias[col];
#pragma unroll
      for (int m = 0; m < 4; m++) {
        int row = m0 + wr + m * 16 + g * 4;
#pragma unroll
        for (int r = 0; r < 4; r++)
          __builtin_nontemporal_store(acc[m][n][r] + bv,
                                      &O[(size_t)(row + r) * 1024 + col]);
      }
    }
  }
}

// ---------------- banded flash attention, fixed-max softmax ------------
// Q: [8192][1024] bf16, PRE-SCALED by 0.125*log2(e). K: [8192][1024] bf16.
// Vt: [4096][2048] bf16 (row = b*1024+h*64+d, col = l). Ow: [8192][1024] bf16.
// Band: kv0 in [q0-256, q0+320). Fixed-max softmax (see round-4 notes).
// GRID: blockIdx.x = bh (64), blockIdx.y = q-tile (32) -> XCD = bh%8, so all
// q-tiles sharing a head's K/V land on ONE XCD -> K/V fetched once per XCD
// instead of 8x (round-7 FETCH=145MB == zero L2 reuse).
// K/V double-buffered: stage(t+1) issued after the top-of-iter barrier,
// drained by the NEXT iter's barrier -> full tile of latency cover.
__launch_bounds__(256, 2)
__global__ void flash_attn(const uint16_t* __restrict__ Qw, const uint16_t* __restrict__ Kw,
                           const uint16_t* __restrict__ Vt, uint16_t* __restrict__ Ow)
{
  __shared__ uint16_t Ks[2][64 * 64];
  __shared__ uint16_t Vs[2][64 * 64];
  __shared__ uint16_t Ps[4][16 * 64];

  const float C2 = 0.14426950408889635f;  // 0.1*log2(e)
  const float C3 = 20.1977305724455f;     // 14*log2(e)

  const int tid = threadIdx.x;
  const int wave = tid >> 6, lane = tid & 63;
  const int g = lane >> 4, li = lane & 15;
  const int bh = blockIdx.x;
  const int q0 = blockIdx.y * 64;
  const int b = bh >> 4, h = bh & 15;

  // Q fragments (A operand): lane row = li (q), k = kc*32 + g*8 .. +8 (d)
  const uint16_t* Qp = Qw + (size_t)(b * 2048 + q0 + wave * 16 + li) * 1024 + h * 64 + g * 8;
  bf16x8 qf0 = *(const bf16x8*)Qp;
  bf16x8 qf1 = *(const bf16x8*)(Qp + 32);

  float l_r[4] = {0.f, 0.f, 0.f, 0.f};   // per-lane partial row sums
  f32x4 o[4];
#pragma unroll
  for (int nd = 0; nd < 4; nd++) o[nd] = f32x4{0.f, 0.f, 0.f, 0.f};

  // staging map: 512 chunks per 64x64 tile; row=chunk>>3, c=chunk&7, src=c^(row&7)
  const int cid0 = tid, cid1 = 256 + tid;
  const int kr0 = cid0 >> 3, c0 = cid0 & 7;
  const int kr1 = cid1 >> 3, c1 = cid1 & 7;
  const int sc0 = c0 ^ (kr0 & 7), sc1 = c1 ^ (kr1 & 7);

  const uint16_t* Kb0 = Kw + (size_t)(b * 2048 + kr0) * 1024 + h * 64 + sc0 * 8;
  const uint16_t* Kb1 = Kw + (size_t)(b * 2048 + kr1) * 1024 + h * 64 + sc1 * 8;
  const uint16_t* Vb0 = Vt + (size_t)(bh * 64 + kr0) * 2048 + sc0 * 8;
  const uint16_t* Vb1 = Vt + (size_t)(bh * 64 + kr1) * 2048 + sc1 * 8;

  const int kv_lo = (q0 >= 256) ? (q0 - 256) : 0;
  const int kv_hi = (q0 + 320 <= 2048) ? (q0 + 320) : 2048;
  const int ntiles = (kv_hi - kv_lo) >> 6;
  const int tq0 = q0 + wave * 16 + g * 4;   // this lane's first q row

  // prologue: stage tile 0 into buffer 0
  {
    const int kv0 = kv_lo;
    gld_lds16(Kb0 + (size_t)kv0 * 1024, (char*)Ks[0] + cid0 * 16);
    gld_lds16(Kb1 + (size_t)kv0 * 1024, (char*)Ks[0] + cid1 * 16);
    gld_lds16(Vb0 + kv0, (char*)Vs[0] + cid0 * 16);
    gld_lds16(Vb1 + kv0, (char*)Vs[0] + cid1 * 16);
  }

  for (int it = 0; it < ntiles; ++it) {
    __syncthreads();   // buf[it&1] staged (compiler drains vmcnt); prev reads of buf[nxt] done
    const int cur = it & 1;
    if (it + 1 < ntiles) {
      const int kvn = kv_lo + (it + 1) * 64;
      const int nxt = cur ^ 1;
      gld_lds16(Kb0 + (size_t)kvn * 1024, (char*)Ks[nxt] + cid0 * 16);
      gld_lds16(Kb1 + (size_t)kvn * 1024, (char*)Ks[nxt] + cid1 * 16);
      gld_lds16(Vb0 + kvn, (char*)Vs[nxt] + cid0 * 16);
      gld_lds16(Vb1 + kvn, (char*)Vs[nxt] + cid1 * 16);
    }
    const int kv0 = kv_lo + it * 64;

    // S = Q K^T (log2 domain, Q pre-scaled) ; p = exp2(s - C2*|dt| - C3)
    float p[4][4];
#pragma unroll
    for (int n = 0; n < 4; n++) {
      int kr = n * 16 + li;
      bf16x8 bk0 = *(const bf16x8*)((const char*)Ks[cur] + kr * 128 + ((g ^ (kr & 7)) << 4));
      bf16x8 bk1 = *(const bf16x8*)((const char*)Ks[cur] + kr * 128 + (((4 + g) ^ (kr & 7)) << 4));
      f32x4 s = f32x4{0.f, 0.f, 0.f, 0.f};
      s = __builtin_amdgcn_mfma_f32_16x16x32_bf16(qf0, bk0, s, 0, 0, 0);
      s = __builtin_amdgcn_mfma_f32_16x16x32_bf16(qf1, bk1, s, 0, 0, 0);
      float dtb = (float)(tq0 - (kv0 + n * 16 + li));
#pragma unroll
      for (int r = 0; r < 4; r++) {
        float e = exp2f((s[r] - C3) - C2 * fabsf(dtb + (float)r));
        p[n][r] = e;
        l_r[r] += e;
      }
    }

    // P -> bf16 -> per-wave swizzled LDS scratch, re-fragment for PV
#pragma unroll
    for (int n = 0; n < 4; n++)
#pragma unroll
      for (int r = 0; r < 4; r++) {
        int prow = g * 4 + r;
        int c = n * 16 + li;
        Ps[wave][prow * 64 + ((((c >> 3) ^ (prow & 7))) << 3) + (c & 7)] = f2bf(p[n][r]);
      }

    // PV: A = P (row q = li), B = Vt tile (col d = li of nd)
    bf16x8 pa0 = *(const bf16x8*)((const char*)Ps[wave] + li * 128 + ((g ^ (li & 7)) << 4));
    bf16x8 pa1 = *(const bf16x8*)((const char*)Ps[wave] + li * 128 + (((4 + g) ^ (li & 7)) << 4));
#pragma unroll
    for (int nd = 0; nd < 4; nd++) {
      int vr = nd * 16 + li;
      bf16x8 vb0 = *(const bf16x8*)((const char*)Vs[cur] + vr * 128 + ((g ^ (vr & 7)) << 4));
      bf16x8 vb1 = *(const bf16x8*)((const char*)Vs[cur] + vr * 128 + (((4 + g) ^ (vr & 7)) << 4));
      o[nd] = __builtin_amdgcn_mfma_f32_16x16x32_bf16(pa0, vb0, o[nd], 0, 0, 0);
      o[nd] = __builtin_amdgcn_mfma_f32_16x16x32_bf16(pa1, vb1, o[nd], 0, 0, 0);
    }
  }

  // single final l reduction across the 16 lanes of the group
#pragma unroll
  for (int r = 0; r < 4; r++) {
    float l = l_r[r];
    l += __shfl_xor(l, 1);
    l += __shfl_xor(l, 2);
    l += __shfl_xor(l, 4);
    l += __shfl_xor(l, 8);
    float inv = 1.0f / l;
    int qg = b * 2048 + q0 + wave * 16 + g * 4 + r;
#pragma unroll
    for (int nd = 0; nd < 4; nd++)
      __builtin_nontemporal_store(f2bf(o[nd][r] * inv),
                                  &Ow[(size_t)qg * 1024 + h * 64 + nd * 16 + li]);
  }
}

// ---------------- launcher ----------------
// Workspace layout (compact, 35.7 MB): Xb (NX) / Wb (NW) / Vtw (NX); Aws
// aliases Xb. Q/K bf16 live in d_out (2 x 16 MB); dead before the final GEMM.
extern "C" void kernel_launch(void* const* d_in, const int* in_sizes, int n_in,
                              void* d_out, int out_size, void* d_ws, size_t ws_size,
                              hipStream_t stream) {
  const float* q  = (const float*)d_in[0];
  const float* k  = (const float*)d_in[1];
  const float* v  = (const float*)d_in[2];
  const float* Wq = (const float*)d_in[3];
  const float* bq = (const float*)d_in[4];
  const float* Wk = (const float*)d_in[5];
  const float* bk = (const float*)d_in[6];
  const float* Wv = (const float*)d_in[7];
  const float* bv = (const float*)d_in[8];
  const float* Wo = (const float*)d_in[9];
  const float* bo = (const float*)d_in[10];

  const size_t NX = (size_t)8192 * 1024;
  const size_t NW = (size_t)1024 * 1024;

  uint16_t* Xb  = (uint16_t*)d_ws;     // NX
  uint16_t* Wb  = Xb + NX;             // NW
  uint16_t* Vtw = Wb + NW;             // NX
  uint16_t* Aws = Xb;                  // alias: Xb dead after V projection
  uint16_t* Qws = (uint16_t*)d_out;    // NX  (scratch inside d_out)
  uint16_t* Kws = Qws + NX;            // NX

  const int n4x = (int)(NX / 4);   // 2097152
  const int n4w = (int)(NW / 4);   // 262144
  const int gcv = (n4x + n4w) / 256;

  dim3 ggrid(64, 8);
  const float qscale = 0.18033688011112042f;  // 0.125 * log2(e)

  convert2<<<gcv, 256, 0, stream>>>(q, Xb, n4x, Wq, Wb, n4w);
  gemm_bt<<<ggrid, 256, 0, stream>>>(Xb, Wb, bq, Qws, 0, qscale);

  convert2<<<gcv, 256, 0, stream>>>(k, Xb, n4x, Wk, Wb, n4w);
  gemm_bt<<<ggrid, 256, 0, stream>>>(Xb, Wb, bk, Kws, 0, 1.0f);

  convert2<<<gcv, 256, 0, stream>>>(v, Xb, n4x, Wv, Wb, n4w);
  gemm_bt<<<ggrid, 256, 0, stream>>>(Xb, Wb, bv, Vtw, 2, 1.0f);

  flash_attn<<<dim3(64, 32), 256, 0, stream>>>(Qws, Kws, Vtw, Aws);

  convert2<<<n4w / 256, 256, 0, stream>>>(Wo, Wb, n4w, (const float*)0, (uint16_t*)0, 0);
  gemm_bt<<<ggrid, 256, 0, stream>>>(Aws, Wb, bo, d_out, 3, 1.0f);
}

// Round 12
// 309.028 us; speedup vs baseline: 1.1205x; 1.1205x over previous
//
#include <hip/hip_runtime.h>
#include <hip/hip_bf16.h>
#include <stdint.h>

typedef __bf16 bf16x8 __attribute__((ext_vector_type(8)));
typedef float f32x4 __attribute__((ext_vector_type(4)));
typedef uint32_t u32x4 __attribute__((ext_vector_type(4)));

// native RNE f32->bf16 (gfx950: v_cvt_pk_bf16_f32)
__device__ __forceinline__ uint16_t f2bf(float f){
  __bf16 h = (__bf16)f;
  return __builtin_bit_cast(uint16_t, h);
}
// pack two f32 -> bf16 pair (lo, hi) in one u32 (compiler emits v_cvt_pk_bf16_f32)
__device__ __forceinline__ uint32_t pkbf(float lo, float hi){
  return (uint32_t)f2bf(lo) | ((uint32_t)f2bf(hi) << 16);
}

__device__ __forceinline__ void gld_lds16(const void* g, void* l){
  __builtin_amdgcn_global_load_lds((const __attribute__((address_space(1))) void*)g,
                                   (__attribute__((address_space(3))) void*)l, 16, 0, 0);
}

// ------------- f32 -> bf16 conversion, two tensors per launch -------------
__global__ void convert2(const float* __restrict__ s1, uint16_t* __restrict__ d1, int n4_1,
                         const float* __restrict__ s2, uint16_t* __restrict__ d2, int n4_2){
  int i = blockIdx.x * blockDim.x + threadIdx.x;
  const float* s; uint16_t* d;
  if (i < n4_1) { s = s1; d = d1; }
  else { i -= n4_1; if (i >= n4_2) return; s = s2; d = d2; }
  float4 v = ((const float4*)s)[i];
  ushort4 o;
  o.x = f2bf(v.x); o.y = f2bf(v.y); o.z = f2bf(v.z); o.w = f2bf(v.w);
  ((ushort4*)d)[i] = o;
}

// ---------------- bf16 bt-GEMM, 2-phase double-buffered (BK=64) ----------
// C[m][n] = sum_k A[m][k]*W[n][k] + bias[n]
// mode 0: out bf16 [8192][1024], value (acc+bias)*oscale
// mode 2: out = Vt layout [4096][2048] bf16: row = b*1024 + n, col = l
// mode 3: out f32 [8192][1024]
__launch_bounds__(256, 2)
__global__ void gemm_bt(const uint16_t* __restrict__ A, const uint16_t* __restrict__ W,
                        const float* __restrict__ bias, void* __restrict__ out, int mode,
                        float oscale)
{
  __shared__ uint16_t As[2][128 * 64];
  __shared__ uint16_t Ws[2][128 * 64];
  const int tid = threadIdx.x;
  const int wave = tid >> 6, lane = tid & 63;
  const int g = lane >> 4, li = lane & 15;
  const int m0 = blockIdx.x * 128, n0 = blockIdx.y * 128;
  const int wr = (wave >> 1) * 64, wc = (wave & 1) * 64;

  f32x4 acc[4][4];
#pragma unroll
  for (int m = 0; m < 4; m++)
#pragma unroll
    for (int n = 0; n < 4; n++) acc[m][n] = f32x4{0.f, 0.f, 0.f, 0.f};

  const uint16_t* Asrc[4];
  const uint16_t* Wsrc[4];
  int cid[4];
#pragma unroll
  for (int j = 0; j < 4; j++) {
    cid[j] = j * 256 + tid;
    int row = cid[j] >> 3, c = cid[j] & 7;
    int sc = c ^ (row & 7);
    Asrc[j] = A + (size_t)(m0 + row) * 1024 + sc * 8;
    Wsrc[j] = W + (size_t)(n0 + row) * 1024 + sc * 8;
  }

#pragma unroll
  for (int j = 0; j < 4; j++) {
    gld_lds16(Asrc[j], (char*)As[0] + cid[j] * 16);
    gld_lds16(Wsrc[j], (char*)Ws[0] + cid[j] * 16);
  }
  __syncthreads();

  for (int t = 0; t < 16; t++) {
    const int cur = t & 1;
    if (t < 15) {
      const int k1 = (t + 1) * 64;
      const int nxt = cur ^ 1;
#pragma unroll
      for (int j = 0; j < 4; j++) {
        gld_lds16(Asrc[j] + k1, (char*)As[nxt] + cid[j] * 16);
        gld_lds16(Wsrc[j] + k1, (char*)Ws[nxt] + cid[j] * 16);
      }
    }

    const char* Ab = (const char*)As[cur];
    const char* Wb = (const char*)Ws[cur];
#pragma unroll
    for (int kh = 0; kh < 2; kh++) {
      bf16x8 a[4], bfr[4];
#pragma unroll
      for (int m = 0; m < 4; m++) {
        int row = wr + m * 16 + li;
        int ch = (kh * 4 + g) ^ (row & 7);
        a[m] = *(const bf16x8*)(Ab + row * 128 + ch * 16);
      }
#pragma unroll
      for (int n = 0; n < 4; n++) {
        int row = wc + n * 16 + li;
        int ch = (kh * 4 + g) ^ (row & 7);
        bfr[n] = *(const bf16x8*)(Wb + row * 128 + ch * 16);
      }
#pragma unroll
      for (int m = 0; m < 4; m++)
#pragma unroll
        for (int n = 0; n < 4; n++)
          acc[m][n] = __builtin_amdgcn_mfma_f32_16x16x32_bf16(a[m], bfr[n], acc[m][n], 0, 0, 0);
    }
    __syncthreads();
  }

  if (mode == 0) {
    uint16_t* O = (uint16_t*)out;
#pragma unroll
    for (int n = 0; n < 4; n++) {
      int col = n0 + wc + n * 16 + li;
      float bv = bias[col];
#pragma unroll
      for (int m = 0; m < 4; m++) {
        int row = m0 + wr + m * 16 + g * 4;
#pragma unroll
        for (int r = 0; r < 4; r++)
          O[(size_t)(row + r) * 1024 + col] = f2bf((acc[m][n][r] + bv) * oscale);
      }
    }
  } else if (mode == 2) {
    uint16_t* O = (uint16_t*)out;
#pragma unroll
    for (int n = 0; n < 4; n++) {
      int col = n0 + wc + n * 16 + li;
      float bv = bias[col];
#pragma unroll
      for (int m = 0; m < 4; m++) {
        int mg = m0 + wr + m * 16 + g * 4;
        int bidx = mg >> 11;
        int l = mg & 2047;
        ushort4 pk;
        pk.x = f2bf(acc[m][n][0] + bv);
        pk.y = f2bf(acc[m][n][1] + bv);
        pk.z = f2bf(acc[m][n][2] + bv);
        pk.w = f2bf(acc[m][n][3] + bv);
        *(ushort4*)(O + ((size_t)bidx * 1024 + col) * 2048 + l) = pk;
      }
    }
  } else {
    float* O = (float*)out;
#pragma unroll
    for (int n = 0; n < 4; n++) {
      int col = n0 + wc + n * 16 + li;
      float bv = bias[col];
#pragma unroll
      for (int m = 0; m < 4; m++) {
        int row = m0 + wr + m * 16 + g * 4;
#pragma unroll
        for (int r = 0; r < 4; r++)
          O[(size_t)(row + r) * 1024 + col] = acc[m][n][r] + bv;
      }
    }
  }
}

// ---------------- banded flash attention, swapped-QK^T, in-register P ----
// Q: [8192][1024] bf16 PRE-SCALED by 0.125*log2(e). K: [8192][1024] bf16.
// Vt: [4096][2048] bf16 (row = b*1024+h*64+d, col = l). Ow: [8192][1024] bf16.
// Band: kv0 in [q0-256, q0+320). Fixed-max softmax (round-4 notes).
// Grid: x = bh (64), y = q-tile (32) -> XCD = bh%8: K/V L2-local per XCD
// (round-9: FETCH 145->24.6MB).
// SWAPPED QK^T (T12): s = mfma(K_frag, Q_frag) -> C row = k (n*16+g*4+r),
// col = q = li. Each lane then holds P[k][q=own li]; the PV A-fragment
// (P[q=li][k=g*8+j]) is assembled IN REGISTERS via cvt_pk pairs + 16 shfl
// + selects -- deletes the per-tile LDS P round-trip (16 ds_write_b16 +
// lgkm drain + ds_read) that was the round-9 serialization stall.
__launch_bounds__(256, 2)
__global__ void flash_attn(const uint16_t* __restrict__ Qw, const uint16_t* __restrict__ Kw,
                           const uint16_t* __restrict__ Vt, uint16_t* __restrict__ Ow)
{
  __shared__ uint16_t Ks[2][64 * 64];
  __shared__ uint16_t Vs[2][64 * 64];

  const float C2 = 0.14426950408889635f;  // 0.1*log2(e)
  const float C3 = 20.1977305724455f;     // 14*log2(e)

  const int tid = threadIdx.x;
  const int wave = tid >> 6, lane = tid & 63;
  const int g = lane >> 4, li = lane & 15;
  const int bh = blockIdx.x;
  const int q0 = blockIdx.y * 64;
  const int b = bh >> 4, h = bh & 15;

  // Q registers; used as the B-operand of the swapped QK^T (col = q = li)
  const uint16_t* Qp = Qw + (size_t)(b * 2048 + q0 + wave * 16 + li) * 1024 + h * 64 + g * 8;
  bf16x8 qf0 = *(const bf16x8*)Qp;
  bf16x8 qf1 = *(const bf16x8*)(Qp + 32);

  float l_own = 0.f;           // partial row-sum for q = li (summed over this lane's k)
  f32x4 o[4];
#pragma unroll
  for (int nd = 0; nd < 4; nd++) o[nd] = f32x4{0.f, 0.f, 0.f, 0.f};

  // staging map: 512 chunks per 64x64 tile; row=chunk>>3, c=chunk&7, src=c^(row&7)
  const int cid0 = tid, cid1 = 256 + tid;
  const int kr0 = cid0 >> 3, c0 = cid0 & 7;
  const int kr1 = cid1 >> 3, c1 = cid1 & 7;
  const int sc0 = c0 ^ (kr0 & 7), sc1 = c1 ^ (kr1 & 7);

  const uint16_t* Kb0 = Kw + (size_t)(b * 2048 + kr0) * 1024 + h * 64 + sc0 * 8;
  const uint16_t* Kb1 = Kw + (size_t)(b * 2048 + kr1) * 1024 + h * 64 + sc1 * 8;
  const uint16_t* Vb0 = Vt + (size_t)(bh * 64 + kr0) * 2048 + sc0 * 8;
  const uint16_t* Vb1 = Vt + (size_t)(bh * 64 + kr1) * 2048 + sc1 * 8;

  const int kv_lo = (q0 >= 256) ? (q0 - 256) : 0;
  const int kv_hi = (q0 + 320 <= 2048) ? (q0 + 320) : 2048;
  const int ntiles = (kv_hi - kv_lo) >> 6;
  const int tq = q0 + wave * 16 + li;       // this lane's q row (swapped layout)
  const int sA = li + 32 * (g & 1);         // shfl source lanes for pa assembly
  const int sB = sA + 16;
  const bool gsel = (g < 2);                // selects n-family (g>>1)

  // prologue: stage tile 0 into buffer 0
  gld_lds16(Kb0 + (size_t)kv_lo * 1024, (char*)Ks[0] + cid0 * 16);
  gld_lds16(Kb1 + (size_t)kv_lo * 1024, (char*)Ks[0] + cid1 * 16);
  gld_lds16(Vb0 + kv_lo, (char*)Vs[0] + cid0 * 16);
  gld_lds16(Vb1 + kv_lo, (char*)Vs[0] + cid1 * 16);

  for (int it = 0; it < ntiles; ++it) {
    __syncthreads();   // buf[it&1] staged (vmcnt drained); prev reads of other buf done
    const int cur = it & 1;
    if (it + 1 < ntiles) {
      const int kvn = kv_lo + (it + 1) * 64;
      const int nxt = cur ^ 1;
      gld_lds16(Kb0 + (size_t)kvn * 1024, (char*)Ks[nxt] + cid0 * 16);
      gld_lds16(Kb1 + (size_t)kvn * 1024, (char*)Ks[nxt] + cid1 * 16);
      gld_lds16(Vb0 + kvn, (char*)Vs[nxt] + cid0 * 16);
      gld_lds16(Vb1 + kvn, (char*)Vs[nxt] + cid1 * 16);
    }
    const int kv0 = kv_lo + it * 64;

    // S^T = K Q^T (log2 domain): per n, C row = k = n*16+g*4+r, col = q = li
    uint32_t w0[4], w1[4];   // packed bf16 pairs: w0[n]=(p[n][0],p[n][1]) w1[n]=(p[n][2],p[n][3])
#pragma unroll
    for (int n = 0; n < 4; n++) {
      int kr = n * 16 + li;
      bf16x8 bk0 = *(const bf16x8*)((const char*)Ks[cur] + kr * 128 + ((g ^ (kr & 7)) << 4));
      bf16x8 bk1 = *(const bf16x8*)((const char*)Ks[cur] + kr * 128 + (((4 + g) ^ (kr & 7)) << 4));
      f32x4 s = f32x4{0.f, 0.f, 0.f, 0.f};
      s = __builtin_amdgcn_mfma_f32_16x16x32_bf16(bk0, qf0, s, 0, 0, 0);   // swapped!
      s = __builtin_amdgcn_mfma_f32_16x16x32_bf16(bk1, qf1, s, 0, 0, 0);
      float dtb = (float)(tq - (kv0 + n * 16 + g * 4));
      float p0 = exp2f((s[0] - C3) - C2 * fabsf(dtb));
      float p1 = exp2f((s[1] - C3) - C2 * fabsf(dtb - 1.f));
      float p2 = exp2f((s[2] - C3) - C2 * fabsf(dtb - 2.f));
      float p3 = exp2f((s[3] - C3) - C2 * fabsf(dtb - 3.f));
      l_own += (p0 + p1) + (p2 + p3);
      w0[n] = pkbf(p0, p1);
      w1[n] = pkbf(p2, p3);
    }

    // assemble PV A-fragments in registers:
    // pa0 word j covers k = g*8+2j (+1); source lane sA (j<2) / sB (j>=2),
    // word w{j&1}[n] with n = g>>1 (pa0) or 2+(g>>1) (pa1).
    u32x4 pa0u, pa1u;
    {
      uint32_t a0 = __shfl((int)w0[0], sA), b0 = __shfl((int)w0[1], sA);
      uint32_t a1 = __shfl((int)w1[0], sA), b1 = __shfl((int)w1[1], sA);
      uint32_t a2 = __shfl((int)w0[0], sB), b2 = __shfl((int)w0[1], sB);
      uint32_t a3 = __shfl((int)w1[0], sB), b3 = __shfl((int)w1[1], sB);
      pa0u.x = gsel ? a0 : b0;  pa0u.y = gsel ? a1 : b1;
      pa0u.z = gsel ? a2 : b2;  pa0u.w = gsel ? a3 : b3;
      uint32_t c0_ = __shfl((int)w0[2], sA), d0 = __shfl((int)w0[3], sA);
      uint32_t c1_ = __shfl((int)w1[2], sA), d1 = __shfl((int)w1[3], sA);
      uint32_t c2_ = __shfl((int)w0[2], sB), d2 = __shfl((int)w0[3], sB);
      uint32_t c3_ = __shfl((int)w1[2], sB), d3 = __shfl((int)w1[3], sB);
      pa1u.x = gsel ? c0_ : d0;  pa1u.y = gsel ? c1_ : d1;
      pa1u.z = gsel ? c2_ : d2;  pa1u.w = gsel ? c3_ : d3;
    }
    bf16x8 pa0 = __builtin_bit_cast(bf16x8, pa0u);
    bf16x8 pa1 = __builtin_bit_cast(bf16x8, pa1u);

    // PV: A = P frag, B = Vt tile (col d = nd*16+li); C row = q = g*4+r
#pragma unroll
    for (int nd = 0; nd < 4; nd++) {
      int vr = nd * 16 + li;
      bf16x8 vb0 = *(const bf16x8*)((const char*)Vs[cur] + vr * 128 + ((g ^ (vr & 7)) << 4));
      bf16x8 vb1 = *(const bf16x8*)((const char*)Vs[cur] + vr * 128 + (((4 + g) ^ (vr & 7)) << 4));
      o[nd] = __builtin_amdgcn_mfma_f32_16x16x32_bf16(pa0, vb0, o[nd], 0, 0, 0);
      o[nd] = __builtin_amdgcn_mfma_f32_16x16x32_bf16(pa1, vb1, o[nd], 0, 0, 0);
    }
  }

  // l: sum the 4 g-lanes holding partials for each q=li, then fetch per-row
  float l_full = l_own;
  l_full += __shfl_xor(l_full, 16);
  l_full += __shfl_xor(l_full, 32);   // now lane holds full l for q = li

#pragma unroll
  for (int r = 0; r < 4; r++) {
    // o row r corresponds to q-row g*4+r; its l lives at lanes with li = g*4+r
    float lr = __shfl(l_full, (lane & 48) | (g * 4 + r));
    float inv = 1.0f / lr;
    int qg = b * 2048 + q0 + wave * 16 + g * 4 + r;
#pragma unroll
    for (int nd = 0; nd < 4; nd++)
      Ow[(size_t)qg * 1024 + h * 64 + nd * 16 + li] = f2bf(o[nd][r] * inv);
  }
}

// ---------------- launcher ----------------
// Workspace (35.7 MB): Xb (NX) / Wb (NW) / Vtw (NX); Aws aliases Xb.
// Q/K bf16 live in d_out (2 x 16 MB); dead before the final GEMM.
extern "C" void kernel_launch(void* const* d_in, const int* in_sizes, int n_in,
                              void* d_out, int out_size, void* d_ws, size_t ws_size,
                              hipStream_t stream) {
  const float* q  = (const float*)d_in[0];
  const float* k  = (const float*)d_in[1];
  const float* v  = (const float*)d_in[2];
  const float* Wq = (const float*)d_in[3];
  const float* bq = (const float*)d_in[4];
  const float* Wk = (const float*)d_in[5];
  const float* bk = (const float*)d_in[6];
  const float* Wv = (const float*)d_in[7];
  const float* bv = (const float*)d_in[8];
  const float* Wo = (const float*)d_in[9];
  const float* bo = (const float*)d_in[10];

  const size_t NX = (size_t)8192 * 1024;
  const size_t NW = (size_t)1024 * 1024;

  uint16_t* Xb  = (uint16_t*)d_ws;
  uint16_t* Wb  = Xb + NX;
  uint16_t* Vtw = Wb + NW;
  uint16_t* Aws = Xb;
  uint16_t* Qws = (uint16_t*)d_out;
  uint16_t* Kws = Qws + NX;

  const int n4x = (int)(NX / 4);
  const int n4w = (int)(NW / 4);
  const int gcv = (n4x + n4w) / 256;

  dim3 ggrid(64, 8);
  const float qscale = 0.18033688011112042f;  // 0.125 * log2(e)

  convert2<<<gcv, 256, 0, stream>>>(q, Xb, n4x, Wq, Wb, n4w);
  gemm_bt<<<ggrid, 256, 0, stream>>>(Xb, Wb, bq, Qws, 0, qscale);

  convert2<<<gcv, 256, 0, stream>>>(k, Xb, n4x, Wk, Wb, n4w);
  gemm_bt<<<ggrid, 256, 0, stream>>>(Xb, Wb, bk, Kws, 0, 1.0f);

  convert2<<<gcv, 256, 0, stream>>>(v, Xb, n4x, Wv, Wb, n4w);
  gemm_bt<<<ggrid, 256, 0, stream>>>(Xb, Wb, bv, Vtw, 2, 1.0f);

  flash_attn<<<dim3(64, 32), 256, 0, stream>>>(Qws, Kws, Vtw, Aws);

  convert2<<<n4w / 256, 256, 0, stream>>>(Wo, Wb, n4w, (const float*)0, (uint16_t*)0, 0);
  gemm_bt<<<ggrid, 256, 0, stream>>>(Aws, Wb, bo, d_out, 3, 1.0f);
}